// Round 1
// baseline (115.373 us; speedup 1.0000x reference)
//
#include <hip/hip_runtime.h>

#define NR_ACTIONS 64
#define VEC 512
#define MC 48          // rows staged per chunk (binomial(2048,1/64): mean 32, std 5.6 -> >48 is ~0.3%)
#define COLS 128       // output columns per tile
#define NTILES (VEC / COLS)

// ---------------- Kernel A: counting-sort batch indices by action ----------------
__global__ void bin_actions(const int* __restrict__ action, int batch,
                            int* __restrict__ offsets, int* __restrict__ sorted) {
    __shared__ int cnt[NR_ACTIONS];
    __shared__ int base[NR_ACTIONS + 1];
    const int tid = threadIdx.x;
    if (tid < NR_ACTIONS) cnt[tid] = 0;
    __syncthreads();
    for (int b = tid; b < batch; b += blockDim.x)
        atomicAdd(&cnt[action[b]], 1);
    __syncthreads();
    if (tid == 0) {
        int run = 0;
        for (int i = 0; i < NR_ACTIONS; ++i) { base[i] = run; run += cnt[i]; }
        base[NR_ACTIONS] = run;
    }
    __syncthreads();
    if (tid <= NR_ACTIONS) offsets[tid] = base[tid];
    if (tid < NR_ACTIONS) cnt[tid] = base[tid];   // reuse as cursor
    __syncthreads();
    for (int b = tid; b < batch; b += blockDim.x) {
        int pos = atomicAdd(&cnt[action[b]], 1);  // order within bin irrelevant
        sorted[pos] = b;
    }
}

// ---------------- Kernel B: per-action grouped GEMM (fp32 VALU) ----------------
// Block = 256 threads: j = tid&127 (column in tile), h = tid>>7 (k-half).
// Each block: action a = blockIdx.y, column tile j0 = blockIdx.x*COLS.
// Stage MC v-rows in LDS, stream W[a][:, tile] from global exactly once per chunk.
__global__ __launch_bounds__(256) void grouped_vm(
    const float* __restrict__ v, const float* __restrict__ W,
    const int* __restrict__ offsets, const int* __restrict__ sorted,
    float* __restrict__ out) {
    __shared__ float vtile[MC][VEC];   // 96 KB
    __shared__ float red[MC][COLS];    // 24 KB
    const int a   = blockIdx.y;
    const int j0  = blockIdx.x * COLS;
    const int tid = threadIdx.x;
    const int j   = tid & (COLS - 1);
    const int h   = tid >> 7;
    const int start = offsets[a];
    const int m     = offsets[a + 1] - start;
    if (m == 0) return;
    const float* wcol = W + (size_t)a * VEC * VEC + j0 + j;

    for (int c0 = 0; c0 < m; c0 += MC) {
        const int mc = min(MC, m - c0);
        __syncthreads();  // protect vtile/red reuse across chunks
        // ---- stage v rows (zero-pad tail rows) ----
        for (int i = tid; i < MC * (VEC / 4); i += 256) {
            const int r  = i >> 7;           // / (VEC/4)
            const int c4 = i & (VEC / 4 - 1);
            float4 val = make_float4(0.f, 0.f, 0.f, 0.f);
            if (r < mc) {
                const int b = sorted[start + c0 + r];
                val = *(const float4*)(v + (size_t)b * VEC + c4 * 4);
            }
            *(float4*)&vtile[r][c4 * 4] = val;
        }
        __syncthreads();
        // ---- compute: this thread's k-half over 48 rows ----
        float acc[MC];
#pragma unroll
        for (int r = 0; r < MC; ++r) acc[r] = 0.f;
        const int kbeg = h * (VEC / 2);
        for (int k = kbeg; k < kbeg + VEC / 2; k += 4) {
            const float w0 = wcol[(size_t)(k + 0) * VEC];
            const float w1 = wcol[(size_t)(k + 1) * VEC];
            const float w2 = wcol[(size_t)(k + 2) * VEC];
            const float w3 = wcol[(size_t)(k + 3) * VEC];
#pragma unroll
            for (int r = 0; r < MC; ++r) {
                const float4 vv = *(const float4*)&vtile[r][k];  // wave-broadcast read
                acc[r] = fmaf(vv.x, w0, acc[r]);
                acc[r] = fmaf(vv.y, w1, acc[r]);
                acc[r] = fmaf(vv.z, w2, acc[r]);
                acc[r] = fmaf(vv.w, w3, acc[r]);
            }
        }
        // ---- reduce k-halves, store ----
        if (h == 1) {
#pragma unroll
            for (int r = 0; r < MC; ++r) red[r][j] = acc[r];
        }
        __syncthreads();
        if (h == 0) {
            for (int r = 0; r < MC; ++r) {
                if (r < mc) {
                    const int b = sorted[start + c0 + r];
                    out[(size_t)b * VEC + j0 + j] = acc[r] + red[r][j];
                }
            }
        }
    }
}

// ---------------- Fallback: naive per-row (used only if ws too small) ----------------
__global__ void naive_vm(const float* __restrict__ v, const float* __restrict__ W,
                         const int* __restrict__ action, float* __restrict__ out) {
    const int b = blockIdx.x;
    const int a = action[b];
    const float* wbase = W + (size_t)a * VEC * VEC;
    const float* vb = v + (size_t)b * VEC;
    const int j = threadIdx.x;
    float acc0 = 0.f, acc1 = 0.f;
    for (int k = 0; k < VEC; ++k) {
        const float vk = vb[k];
        acc0 = fmaf(vk, wbase[(size_t)k * VEC + j], acc0);
        acc1 = fmaf(vk, wbase[(size_t)k * VEC + j + 256], acc1);
    }
    out[(size_t)b * VEC + j] = acc0;
    out[(size_t)b * VEC + j + 256] = acc1;
}

extern "C" void kernel_launch(void* const* d_in, const int* in_sizes, int n_in,
                              void* d_out, int out_size, void* d_ws, size_t ws_size,
                              hipStream_t stream) {
    const float* v      = (const float*)d_in[0];
    const int*   action = (const int*)d_in[1];
    const float* W      = (const float*)d_in[2];
    float* out = (float*)d_out;
    const int batch = in_sizes[1];

    const size_t ws_needed = (size_t)(NR_ACTIONS + 1 + batch) * sizeof(int);
    if (ws_size < ws_needed) {
        naive_vm<<<batch, 256, 0, stream>>>(v, W, action, out);
        return;
    }
    int* offsets = (int*)d_ws;
    int* sorted  = offsets + (NR_ACTIONS + 1);

    bin_actions<<<1, 256, 0, stream>>>(action, batch, offsets, sorted);
    grouped_vm<<<dim3(NTILES, NR_ACTIONS), 256, 0, stream>>>(v, W, offsets, sorted, out);
}

// Round 2
// 34.913 us; speedup vs baseline: 3.3046x; 3.3046x over previous
//
#include <hip/hip_runtime.h>

#define NR_ACTIONS 64
#define VEC 512
#define NTILE 64            // output columns per block
#define MTILE 64            // batch rows per M-iteration
#define KSTEP 128           // K-chunk staged in LDS
#define KCH (VEC / KSTEP)   // 4
#define LPITCH (KSTEP + 8)  // 136 elems = 272 B: keeps 16B alignment, spreads banks

typedef short bf16x8 __attribute__((ext_vector_type(8)));
typedef float f32x4  __attribute__((ext_vector_type(4)));

__device__ __forceinline__ ushort f2bf(float f) {
    union { float f; uint32_t u; } x; x.f = f;
    uint32_t r = x.u + 0x7FFFu + ((x.u >> 16) & 1u);   // round-to-nearest-even
    return (ushort)(r >> 16);
}
__device__ __forceinline__ uint2 pack4(float a, float b, float c, float d) {
    uint2 r;
    r.x = (uint32_t)f2bf(a) | ((uint32_t)f2bf(b) << 16);
    r.y = (uint32_t)f2bf(c) | ((uint32_t)f2bf(d) << 16);
    return r;
}

// ---------------- Kernel A: counting-sort batch indices by action ----------------
__global__ void bin_actions(const int* __restrict__ action, int batch,
                            int* __restrict__ offsets, int* __restrict__ sorted) {
    __shared__ int cnt[NR_ACTIONS];
    __shared__ int base[NR_ACTIONS + 1];
    const int tid = threadIdx.x;
    if (tid < NR_ACTIONS) cnt[tid] = 0;
    __syncthreads();
    for (int b = tid; b < batch; b += blockDim.x)
        atomicAdd(&cnt[action[b]], 1);
    __syncthreads();
    if (tid == 0) {
        int run = 0;
        for (int i = 0; i < NR_ACTIONS; ++i) { base[i] = run; run += cnt[i]; }
        base[NR_ACTIONS] = run;
    }
    __syncthreads();
    if (tid <= NR_ACTIONS) offsets[tid] = base[tid];
    if (tid < NR_ACTIONS) cnt[tid] = base[tid];
    __syncthreads();
    for (int b = tid; b < batch; b += blockDim.x) {
        int pos = atomicAdd(&cnt[action[b]], 1);
        sorted[pos] = b;
    }
}

// ---------------- Kernel B: grouped GEMM via bf16 MFMA ----------------
// Block: 256 threads = 4 waves. blockIdx = (n-tile, action).
// Wave w owns output cols [j0 + w*16, +16). M-tile 64 rows, K streamed in 128-chunks.
// LDS: sA[64][136] v-rows bf16, sB[64][136] = W^T chunk bf16. 35 KB total.
__global__ __launch_bounds__(256) void grouped_mfma(
    const float* __restrict__ v, const float* __restrict__ W,
    const int* __restrict__ offsets, const int* __restrict__ sorted,
    float* __restrict__ out)
{
    __shared__ ushort sA[MTILE * LPITCH];
    __shared__ ushort sB[NTILE * LPITCH];

    const int a    = blockIdx.y;
    const int j0   = blockIdx.x * NTILE;
    const int tid  = threadIdx.x;
    const int lane = tid & 63;
    const int w    = tid >> 6;
    const int start = offsets[a];
    const int m     = offsets[a + 1] - start;
    if (m == 0) return;

    const float* Wa = W + (size_t)a * VEC * VEC;

    for (int mbase = 0; mbase < m; mbase += MTILE) {
        const int mrem = m - mbase;
        const int nrb  = min(4, (mrem + 15) >> 4);   // active 16-row blocks

        // v staging assignment: 4 threads per row, 8 float4 each
        const int vrow = tid >> 2;                    // 0..63
        const bool vok = vrow < mrem;
        const float* vptr = v + (size_t)(vok ? sorted[start + mbase + vrow] : 0) * VEC;

        f32x4 acc[4];
#pragma unroll
        for (int r = 0; r < 4; ++r) acc[r] = (f32x4){0.f, 0.f, 0.f, 0.f};

        float4 vv[8], wv[8];
        // ---- prologue: issue chunk-0 loads ----
#pragma unroll
        for (int i = 0; i < 8; ++i) {
            const int kf = (tid & 3) + 4 * i;
            vv[i] = vok ? *(const float4*)(vptr + kf * 4)
                        : make_float4(0.f, 0.f, 0.f, 0.f);
        }
#pragma unroll
        for (int p = 0; p < 2; ++p)
#pragma unroll
            for (int i = 0; i < 4; ++i) {
                const int kk = p * 64 + (tid >> 4) * 4 + i;
                wv[p * 4 + i] = *(const float4*)(Wa + (size_t)kk * VEC + j0 + 4 * (tid & 15));
            }

        for (int kc = 0; kc < KCH; ++kc) {
            __syncthreads();   // previous chunk's compute done -> LDS reusable
            // ---- regs -> LDS (fp32 -> bf16) ----
#pragma unroll
            for (int i = 0; i < 8; ++i)
                *(uint2*)&sA[vrow * LPITCH + 4 * (tid & 3) + 16 * i] =
                    pack4(vv[i].x, vv[i].y, vv[i].z, vv[i].w);
#pragma unroll
            for (int p = 0; p < 2; ++p)
#pragma unroll
                for (int c = 0; c < 4; ++c) {
                    const int col = 4 * (tid & 15) + c;
                    const int kl  = p * 64 + (tid >> 4) * 4;
                    *(uint2*)&sB[col * LPITCH + kl] =
                        pack4((&wv[p * 4 + 0].x)[c], (&wv[p * 4 + 1].x)[c],
                              (&wv[p * 4 + 2].x)[c], (&wv[p * 4 + 3].x)[c]);
                }
            __syncthreads();
            // ---- issue next chunk's loads (in flight under the MFMAs) ----
            if (kc + 1 < KCH) {
                const int kb = (kc + 1) * KSTEP;
#pragma unroll
                for (int i = 0; i < 8; ++i) {
                    const int kf = (tid & 3) + 4 * i;
                    vv[i] = vok ? *(const float4*)(vptr + kb + kf * 4)
                                : make_float4(0.f, 0.f, 0.f, 0.f);
                }
#pragma unroll
                for (int p = 0; p < 2; ++p)
#pragma unroll
                    for (int i = 0; i < 4; ++i) {
                        const int kk = kb + p * 64 + (tid >> 4) * 4 + i;
                        wv[p * 4 + i] = *(const float4*)(Wa + (size_t)kk * VEC + j0 + 4 * (tid & 15));
                    }
            }
            // ---- compute chunk kc: 4 k-steps x nrb MFMAs ----
#pragma unroll
            for (int ks = 0; ks < KSTEP / 32; ++ks) {
                const int koff = ks * 32 + (lane >> 4) * 8;
                const bf16x8 bfrag =
                    *(const bf16x8*)&sB[(w * 16 + (lane & 15)) * LPITCH + koff];
#pragma unroll
                for (int r = 0; r < 4; ++r) {
                    if (r < nrb) {
                        const bf16x8 afrag =
                            *(const bf16x8*)&sA[(r * 16 + (lane & 15)) * LPITCH + koff];
                        acc[r] = __builtin_amdgcn_mfma_f32_16x16x32_bf16(
                            afrag, bfrag, acc[r], 0, 0, 0);
                    }
                }
            }
        }

        // ---- store: D layout col=lane&15, row=(lane>>4)*4+q (m89-verified) ----
        const int colg = j0 + w * 16 + (lane & 15);
#pragma unroll
        for (int r = 0; r < 4; ++r) {
            if (r < nrb) {
#pragma unroll
                for (int q = 0; q < 4; ++q) {
                    const int row_l = mbase + r * 16 + (lane >> 4) * 4 + q;
                    if (row_l < m)
                        out[(size_t)sorted[start + row_l] * VEC + colg] = acc[r][q];
                }
            }
        }
    }
}

// ---------------- Fallback: naive per-row (used only if ws too small) ----------------
__global__ void naive_vm(const float* __restrict__ v, const float* __restrict__ W,
                         const int* __restrict__ action, float* __restrict__ out) {
    const int b = blockIdx.x;
    const int a = action[b];
    const float* wbase = W + (size_t)a * VEC * VEC;
    const float* vb = v + (size_t)b * VEC;
    const int j = threadIdx.x;
    float acc0 = 0.f, acc1 = 0.f;
    for (int k = 0; k < VEC; ++k) {
        const float vk = vb[k];
        acc0 = fmaf(vk, wbase[(size_t)k * VEC + j], acc0);
        acc1 = fmaf(vk, wbase[(size_t)k * VEC + j + 256], acc1);
    }
    out[(size_t)b * VEC + j] = acc0;
    out[(size_t)b * VEC + j + 256] = acc1;
}

extern "C" void kernel_launch(void* const* d_in, const int* in_sizes, int n_in,
                              void* d_out, int out_size, void* d_ws, size_t ws_size,
                              hipStream_t stream) {
    const float* v      = (const float*)d_in[0];
    const int*   action = (const int*)d_in[1];
    const float* W      = (const float*)d_in[2];
    float* out = (float*)d_out;
    const int batch = in_sizes[1];

    const size_t ws_needed = (size_t)(NR_ACTIONS + 1 + batch) * sizeof(int);
    if (ws_size < ws_needed) {
        naive_vm<<<batch, 256, 0, stream>>>(v, W, action, out);
        return;
    }
    int* offsets = (int*)d_ws;
    int* sorted  = offsets + (NR_ACTIONS + 1);

    bin_actions<<<1, 256, 0, stream>>>(action, batch, offsets, sorted);
    grouped_mfma<<<dim3(VEC / NTILE, NR_ACTIONS), 256, 0, stream>>>(
        v, W, offsets, sorted, out);
}